// Round 4
// baseline (365.055 us; speedup 1.0000x reference)
//
#include <hip/hip_runtime.h>
#include <math.h>

#define NNODES   50000
#define NFEAT    512
#define NCLASS   256
#define NEG_SLOPE 0.2f
#define MPAD     50048   // 391 * 128

typedef __attribute__((ext_vector_type(8))) short short8;
typedef __attribute__((ext_vector_type(4))) float floatx4;

__device__ __forceinline__ unsigned short f2bf(float f) {
    unsigned u = __builtin_bit_cast(unsigned, f);
    u += 0x7fffu + ((u >> 16) & 1u);          // RNE
    return (unsigned short)(u >> 16);
}
__device__ __forceinline__ float bf2f_lo(unsigned u) {   // low 16 bits -> float
    return __builtin_bit_cast(float, u << 16);
}
__device__ __forceinline__ float bf2f_hi(unsigned u) {   // high 16 bits -> float
    return __builtin_bit_cast(float, u & 0xffff0000u);
}
// pack two floats to bf16 pair, round-half-away (1 v_add each + 1 v_perm)
__device__ __forceinline__ unsigned pack_bf16_rh(float lo, float hi) {
    const unsigned ulo = __builtin_bit_cast(unsigned, lo) + 0x8000u;
    const unsigned uhi = __builtin_bit_cast(unsigned, hi) + 0x8000u;
    return __builtin_amdgcn_perm(uhi, ulo, 0x07060302);
}

// ---------------------------------------------------------------------------
// Init: W [512][256] fp32 -> Wt [256][512] bf16 (transposed), and zero
// the 4*M-int block {s_row, s_col, deg, cursor}. Grid fixed 512x256.
// ---------------------------------------------------------------------------
__global__ __launch_bounds__(256) void init_kernel(const float* __restrict__ W,
                                                   unsigned short* __restrict__ Wt,
                                                   int* __restrict__ zero4, int zn) {
    const int i = blockIdx.x * 256 + threadIdx.x;     // 0..131071
    const int n = i >> 9;
    const int k = i & 511;
    Wt[i] = f2bf(W[(size_t)k * NCLASS + n]);
    for (int j = i; j < zn; j += 131072) zero4[j] = 0;
}

// ---------------------------------------------------------------------------
// MFMA GEMM with fused A-conversion and fused s_row/s_col computation.
// hb = bf16( x[MPAD,512]@W ); s_row += hb.a1, s_col += hb.a2 (atomics).
// 128x128 tile, 4 waves (2x2 of 64x64), BK=32.
// A: fp32 global -> round/pack -> ds_write_b128. B: global_load_lds(16B).
// ---------------------------------------------------------------------------
__global__ __launch_bounds__(256) void gemm_mfma_kernel(const float* __restrict__ x,
                                                        const unsigned short* __restrict__ Wt,
                                                        unsigned short* __restrict__ hb,
                                                        const float* __restrict__ a,
                                                        float* __restrict__ s_row,
                                                        float* __restrict__ s_col, int M) {
    __shared__ short As[128 * 32];   // [row][k]
    __shared__ short Bs[128 * 32];   // [n][k]
    __shared__ short Cs[64 * 132];   // epilogue staging, +4 pad

    const int tid  = threadIdx.x;
    const int w    = tid >> 6;
    const int lane = tid & 63;
    const int rowbase = blockIdx.x * 128;
    const int nbase   = blockIdx.y * 128;

    const int wm = w & 1;
    const int wn = w >> 1;

    const int srow = (lane >> 2);        // 0..15 within seg
    const int skq  = (lane & 3) << 3;    // k offset 0,8,16,24

    const int fm = lane & 15;
    const int fq = lane >> 4;

    floatx4 acc[4][4];
#pragma unroll
    for (int i = 0; i < 4; ++i)
#pragma unroll
        for (int j = 0; j < 4; ++j)
            acc[i][j] = (floatx4){0.f, 0.f, 0.f, 0.f};

    for (int k0 = 0; k0 < NFEAT; k0 += 32) {
#pragma unroll
        for (int t = 0; t < 2; ++t) {
            const int seg = w * 2 + t;
            const int rr  = seg * 16 + srow;
            // B tile: bf16, async direct-to-LDS (lane-dense 16B pattern)
            __builtin_amdgcn_global_load_lds(
                (const __attribute__((address_space(1))) void*)(Wt + (size_t)(nbase + rr) * NFEAT + k0 + skq),
                (__attribute__((address_space(3))) void*)(Bs + seg * 512), 16, 0, 0);
            // A tile: fp32 -> bf16 in-register
            const int ar = min(rowbase + rr, M - 1);
            const float4* xp = (const float4*)&x[(size_t)ar * NFEAT + k0 + skq];
            const float4 u0 = xp[0];
            const float4 u1 = xp[1];
            uint4 o;
            o.x = pack_bf16_rh(u0.x, u0.y);
            o.y = pack_bf16_rh(u0.z, u0.w);
            o.z = pack_bf16_rh(u1.x, u1.y);
            o.w = pack_bf16_rh(u1.z, u1.w);
            *(uint4*)&As[rr * 32 + skq] = o;
        }
        __syncthreads();

        short8 af[4], bfr[4];
#pragma unroll
        for (int mt = 0; mt < 4; ++mt)
            af[mt] = *(const short8*)&As[(wm * 64 + mt * 16 + fm) * 32 + fq * 8];
#pragma unroll
        for (int nt = 0; nt < 4; ++nt)
            bfr[nt] = *(const short8*)&Bs[(wn * 64 + nt * 16 + fm) * 32 + fq * 8];

#pragma unroll
        for (int mt = 0; mt < 4; ++mt)
#pragma unroll
            for (int nt = 0; nt < 4; ++nt)
                acc[mt][nt] = __builtin_amdgcn_mfma_f32_16x16x32_bf16(af[mt], bfr[nt], acc[mt][nt], 0, 0, 0);

        __syncthreads();
    }

    // Epilogue: stage 64x128 bf16 rows in LDS; coalesced stores + fused s dot.
    for (int p = 0; p < 2; ++p) {
        if (p) __syncthreads();
        if (wm == p) {
#pragma unroll
            for (int mt = 0; mt < 4; ++mt)
#pragma unroll
                for (int nt = 0; nt < 4; ++nt)
#pragma unroll
                    for (int r = 0; r < 4; ++r)
                        Cs[(mt * 16 + fq * 4 + r) * 132 + wn * 64 + nt * 16 + fm] =
                            (short)f2bf(acc[mt][nt][r]);
        }
        __syncthreads();
#pragma unroll
        for (int k = 0; k < 8; ++k) {
            const int idx = tid + k * 256;     // 64 rows x 32 chunks of 4
            const int lrow = idx >> 5;
            const int c4 = (idx & 31) << 2;
            const int grow = rowbase + p * 64 + lrow;
            const uint2 vv = *(const uint2*)&Cs[lrow * 132 + c4];
            const float f0 = bf2f_lo(vv.x), f1 = bf2f_hi(vv.x);
            const float f2 = bf2f_lo(vv.y), f3 = bf2f_hi(vv.y);
            const int col = nbase + c4;
            const float4 A1 = *(const float4*)&a[col];
            const float4 A2 = *(const float4*)&a[NCLASS + col];
            float p1 = f0 * A1.x + f1 * A1.y + f2 * A1.z + f3 * A1.w;
            float p2 = f0 * A2.x + f1 * A2.y + f2 * A2.z + f3 * A2.w;
            // 32 threads share one row: segmented shuffle reduce within half-wave
#pragma unroll
            for (int off = 1; off < 32; off <<= 1) {
                p1 += __shfl_xor(p1, off);
                p2 += __shfl_xor(p2, off);
            }
            if (grow < M) {
                *(uint2*)&hb[(size_t)grow * NCLASS + col] = vv;
                if ((lane & 31) == 0) {
                    atomicAdd(&s_row[grow], p1);
                    atomicAdd(&s_col[grow], p2);
                }
            }
        }
    }
}

// ---------------------------------------------------------------------------
// CSR build: histogram -> two-level scan -> scatter(+e)
// ---------------------------------------------------------------------------
__global__ __launch_bounds__(256) void hist_kernel(const int* __restrict__ row,
                                                   int* __restrict__ deg, int e) {
    const int i = blockIdx.x * 256 + threadIdx.x;
    if (i < e) atomicAdd(&deg[row[i]], 1);
}

__global__ __launch_bounds__(256) void scan1_kernel(const int* __restrict__ deg,
                                                    int* __restrict__ tmp,
                                                    int* __restrict__ blocksum, int n) {
    __shared__ int buf[256];
    const int i = blockIdx.x * 256 + threadIdx.x;
    const int t = threadIdx.x;
    buf[t] = (i < n) ? deg[i] : 0;
    __syncthreads();
#pragma unroll
    for (int off = 1; off < 256; off <<= 1) {
        const int u = (t >= off) ? buf[t - off] : 0;
        __syncthreads();
        buf[t] += u;
        __syncthreads();
    }
    if (i < n) tmp[i] = buf[t];
    if (t == 255) blocksum[blockIdx.x] = buf[255];
}

__global__ __launch_bounds__(256) void scan3_kernel(const int* __restrict__ tmp,
                                                    const int* __restrict__ blocksum,
                                                    int* __restrict__ rowstart, int n, int nb) {
    __shared__ int buf[256];
    const int t = threadIdx.x;
    buf[t] = (t < nb) ? blocksum[t] : 0;
    __syncthreads();
#pragma unroll
    for (int off = 1; off < 256; off <<= 1) {
        const int u = (t >= off) ? buf[t - off] : 0;
        __syncthreads();
        buf[t] += u;
        __syncthreads();
    }
    const int boff = (blockIdx.x == 0) ? 0 : buf[blockIdx.x - 1];
    const int i = blockIdx.x * 256 + t;
    if (i < n) rowstart[i + 1] = tmp[i] + boff;
    if (i == 0) rowstart[0] = 0;
}

__global__ __launch_bounds__(256) void scatter_kernel(const int* __restrict__ row,
                                                      const int* __restrict__ col,
                                                      const float* __restrict__ s_row,
                                                      const float* __restrict__ s_col,
                                                      const int* __restrict__ rowstart,
                                                      int* __restrict__ cursor,
                                                      int2* __restrict__ sorted_ce, int e) {
    const int i = blockIdx.x * 256 + threadIdx.x;
    if (i >= e) return;
    const int r = row[i];
    const int c = col[i];
    const float logit = s_row[r] + s_col[c];
    const float lr = logit > 0.f ? logit : NEG_SLOPE * logit;
    const float ew = __expf(-lr);
    const int pos = atomicAdd(&cursor[r], 1);
    int2 v;
    v.x = c;
    v.y = __builtin_bit_cast(int, ew);
    sorted_ce[rowstart[r] + pos] = v;
}

// ---------------------------------------------------------------------------
// Aggregation + elu + log_softmax. TWO waves per row (128 feats each,
// float2/lane) for 2x latency hiding; lse combined across the wave pair.
// Block = 256 threads = 4 waves = 2 rows.
// ---------------------------------------------------------------------------
__global__ __launch_bounds__(256) void aggregate_kernel(const unsigned short* __restrict__ hb,
                                                        const int2* __restrict__ sorted_ce,
                                                        const int* __restrict__ rowstart,
                                                        float* __restrict__ out, int n) {
    __shared__ float xm[4], xs[4];
    const int w    = threadIdx.x >> 6;
    const int lane = threadIdx.x & 63;
    const int r    = min((int)(blockIdx.x * 2 + (w >> 1)), n - 1);
    const int half = w & 1;
    const int fo   = half * 128 + lane * 2;   // feature offset (elements)

    const int jb = rowstart[r];
    const int je = rowstart[r + 1];

    float a0 = 0.f, a1v = 0.f;
    float rowsum = 0.f;

    int j = jb;
    for (; j + 3 < je; j += 4) {
        const int2 v0 = sorted_ce[j];
        const int2 v1 = sorted_ce[j + 1];
        const int2 v2 = sorted_ce[j + 2];
        const int2 v3 = sorted_ce[j + 3];
        const unsigned g0 = *(const unsigned*)&hb[(size_t)v0.x * NCLASS + fo];
        const unsigned g1 = *(const unsigned*)&hb[(size_t)v1.x * NCLASS + fo];
        const unsigned g2 = *(const unsigned*)&hb[(size_t)v2.x * NCLASS + fo];
        const unsigned g3 = *(const unsigned*)&hb[(size_t)v3.x * NCLASS + fo];
        const float e0 = __builtin_bit_cast(float, v0.y);
        const float e1 = __builtin_bit_cast(float, v1.y);
        const float e2 = __builtin_bit_cast(float, v2.y);
        const float e3 = __builtin_bit_cast(float, v3.y);
        rowsum += (e0 + e1) + (e2 + e3);
        a0  += e0 * bf2f_lo(g0) + e1 * bf2f_lo(g1) + e2 * bf2f_lo(g2) + e3 * bf2f_lo(g3);
        a1v += e0 * bf2f_hi(g0) + e1 * bf2f_hi(g1) + e2 * bf2f_hi(g2) + e3 * bf2f_hi(g3);
    }
    for (; j < je; ++j) {
        const int2 v = sorted_ce[j];
        const unsigned g = *(const unsigned*)&hb[(size_t)v.x * NCLASS + fo];
        const float e = __builtin_bit_cast(float, v.y);
        rowsum += e;
        a0  += e * bf2f_lo(g);
        a1v += e * bf2f_hi(g);
    }

    const float inv = 1.f / rowsum;
    float v0 = a0 * inv;
    float v1 = a1v * inv;
    v0 = v0 > 0.f ? v0 : __expf(v0) - 1.f;
    v1 = v1 > 0.f ? v1 : __expf(v1) - 1.f;

    // cross-wave log_softmax over 256 feats
    float m = fmaxf(v0, v1);
#pragma unroll
    for (int off = 32; off > 0; off >>= 1) m = fmaxf(m, __shfl_xor(m, off));
    if (lane == 0) xm[w] = m;
    __syncthreads();
    m = fmaxf(xm[w], xm[w ^ 1]);

    float s = __expf(v0 - m) + __expf(v1 - m);
#pragma unroll
    for (int off = 32; off > 0; off >>= 1) s += __shfl_xor(s, off);
    if (lane == 0) xs[w] = s;
    __syncthreads();
    s = xs[w] + xs[w ^ 1];

    const float lse = m + __logf(s);
    float2 o = make_float2(v0 - lse, v1 - lse);
    *(float2*)&out[(size_t)r * NCLASS + fo] = o;
}

// ---------------------------------------------------------------------------
extern "C" void kernel_launch(void* const* d_in, const int* in_sizes, int n_in,
                              void* d_out, int out_size, void* d_ws, size_t ws_size,
                              hipStream_t stream) {
    const float* x  = (const float*)d_in[0];   // [N, 512]
    const float* W  = (const float*)d_in[1];   // [512, 256]
    const float* a  = (const float*)d_in[2];   // [512]
    const int* edge = (const int*)d_in[3];     // [2, E]
    float* out = (float*)d_out;

    const int M = in_sizes[0] / NFEAT;         // 50000
    const int E = in_sizes[3] / 2;             // 850000
    const int* row = edge;
    const int* col = edge + E;

    char* ws = (char*)d_ws;
    size_t off = 0;
    auto carve = [&](size_t bytes) -> char* {
        char* p = ws + off;
        off = (off + bytes + 255) & ~(size_t)255;
        return p;
    };
    unsigned short* Wt = (unsigned short*)carve((size_t)NCLASS * NFEAT * sizeof(short));
    unsigned short* hb = (unsigned short*)carve((size_t)M * NCLASS * sizeof(short)); // 25.6MB
    int*   zero4    = (int*)carve((size_t)4 * M * sizeof(int));   // s_row,s_col,deg,cursor
    float* s_row    = (float*)zero4;
    float* s_col    = (float*)(zero4 + M);
    int*   deg      = zero4 + 2 * M;
    int*   cursor   = zero4 + 3 * M;
    int*   rowstart = (int*)carve((size_t)(M + 1) * sizeof(int));
    int*   tmp_scan = (int*)carve((size_t)M * sizeof(int));
    int*   blocksum = (int*)carve((size_t)256 * sizeof(int));
    int2*  sorted_ce = (int2*)carve((size_t)E * sizeof(int2));    // 6.8MB

    init_kernel<<<512, 256, 0, stream>>>(W, Wt, zero4, 4 * M);

    dim3 ggrid(MPAD / 128, NCLASS / 128);
    gemm_mfma_kernel<<<ggrid, 256, 0, stream>>>(x, Wt, hb, a, s_row, s_col, M);

    const int nb1 = (M + 255) / 256;   // 196
    hist_kernel<<<(E + 255) / 256, 256, 0, stream>>>(row, deg, E);
    scan1_kernel<<<nb1, 256, 0, stream>>>(deg, tmp_scan, blocksum, M);
    scan3_kernel<<<nb1, 256, 0, stream>>>(tmp_scan, blocksum, rowstart, M, nb1);
    scatter_kernel<<<(E + 255) / 256, 256, 0, stream>>>(row, col, s_row, s_col,
                                                        rowstart, cursor, sorted_ce, E);

    aggregate_kernel<<<(M + 1) / 2, 256, 0, stream>>>(hb, sorted_ce, rowstart, out, M);
}